// Round 6
// baseline (40.616 us; speedup 1.0000x reference)
//
#include <hip/hip_runtime.h>
#include <hip/hip_bf16.h>

#define TT 2048
#define HH 1024
#define NTAGS 74
#define NPAD 80
#define CHK 64            // K elements per chunk
#define NCH (HH / CHK)    // 16 chunks
#define MROWS 128         // rows per block (64 front + 64 mirrored back)
#define THREADS 512

typedef __bf16 bf16x8 __attribute__((ext_vector_type(8)));
typedef float f32x4 __attribute__((ext_vector_type(4)));

// Transpose + convert W_out [1024][74] f32 -> Wt [80][1024] bf16 (pad cols 74..79 = 0)
__global__ __launch_bounds__(256) void prep_w_kernel(const float* __restrict__ W,
                                                     __bf16* __restrict__ Wt) {
    __shared__ float tile[64][80];
    const int k0 = blockIdx.x * 64;
    const int tid = threadIdx.x;
    for (int i = tid; i < 64 * NTAGS; i += 256) {
        int k = i / NTAGS, n = i - k * NTAGS;
        tile[k][n] = W[(k0 + k) * NTAGS + n];
    }
    __syncthreads();
    for (int i = tid; i < NPAD * 64; i += 256) {
        int n = i >> 6, kk = i & 63;
        float v = (n < NTAGS) ? tile[kk][n] : 0.0f;
        Wt[n * HH + k0 + kk] = (__bf16)v;
    }
}

// Fused gather-blend + skinny GEMM [B*T,1024]x[1024,74] via 16x16x32 bf16 MFMA.
// Block = 512 thr (8 waves), M=128 rows = 64 front + 64 mirrored-back rows of one
// batch (load balance: valid-count per block in [64,128] instead of [0,128]).
// Grid = 256 (1 block/CU); W traffic = 256 x 160 KB = 40 MB (2x less than R5).
// K chunks of 64; A double-buffered (2x16KB), W double-buffered (2x10KB), both
// XOR-swizzled (byte ^= (row&7)<<4). Loop: commit regs(ch+1) -> issue loads(ch+2)
// -> compute(ch) -> barrier. Double-buffer is hazard-free: commit targets buffer
// (ch+1)&1, compute reads ch&1 between the same barriers.
__global__ __launch_bounds__(512, 1) void slu_main(const float* __restrict__ out_char,
                                                   const float* __restrict__ out_word,
                                                   const int* __restrict__ word_idx,
                                                   const int* __restrict__ is_head,
                                                   const int* __restrict__ valid_mask,
                                                   const __bf16* __restrict__ Wt,
                                                   const float* __restrict__ b_out,
                                                   float* __restrict__ out) {
    // LDS: A[2] @ 0 (2*16384), W[2] @ 32768 (2*10240) = 53248 B
    __shared__ __align__(16) char smem[53248];
    const int tid = threadIdx.x;
    const int wv = tid >> 6;      // 0..7
    const int lane = tid & 63;
    const int l15 = lane & 15;
    const int kgrp = lane >> 4;

    // mirrored row tiling: block (b, j) -> front 64 rows + back 64 rows of batch b
    const int bid = blockIdx.x;
    const int batch = bid >> 4;
    const int j = bid & 15;
    const int fb = batch * TT + j * 64;              // front base (j*64 <= 960)
    const int bb = batch * TT + TT - (j + 1) * 64;   // back base  (>= 1024)

    // ---- A staging: thread covers local row rloc=(tid>>2) (0..127), k-sub q=(tid&3) ----
    const int rloc = tid >> 2;
    const int q = tid & 3;
    const int r = (rloc < 64) ? (fb + rloc) : (bb + (rloc - 64));
    const int widx = word_idx[r];
    const int val = valid_mask[r];
    const float rt = is_head[r] ? 0.88f : 0.70f;
    const float rate = val ? rt : 0.0f;
    const float crate = val ? (1.0f - rt) : 0.0f;
    const float* cptr = out_char + (size_t)r * HH + q * 16;
    const float* wptr = out_word + ((size_t)batch * TT + widx) * HH + q * 16;
    const int asw = (rloc & 7) << 4;
    const int awr0 = (rloc * 128 + q * 32) ^ asw;
    const int awr1 = (rloc * 128 + q * 32 + 16) ^ asw;

    // ---- W staging: 640 16B-units/chunk over 512 threads; extra 128 units for tid<128 ----
    const int wn0 = tid >> 3, wsb = tid & 7;
    const __bf16* wgp0 = Wt + (size_t)wn0 * HH + wsb * 8;
    const __bf16* wgp1 = wgp0 + 64 * HH;             // rows 64..79 (tid<128)
    const int wsw = (wn0 & 7) << 4;
    const int wwr0 = (wn0 * 128 + wsb * 16) ^ wsw;
    const int wwr1 = ((wn0 + 64) * 128 + wsb * 16) ^ wsw;  // (wn0+64)&7 == wn0&7
    const bool w2 = (tid < 128);

    // ---- fragment read offsets (swizzle matches writes) ----
    const int fsw = (l15 & 7) << 4;
    const int arow = wv * 16 + l15;                  // 0..127
    int aoff[2], woff[2][5];
#pragma unroll
    for (int s = 0; s < 2; ++s) {
        aoff[s] = (arow * 128 + s * 64 + kgrp * 16) ^ fsw;
#pragma unroll
        for (int nt = 0; nt < 5; ++nt)
            woff[s][nt] = ((nt * 16 + l15) * 128 + s * 64 + kgrp * 16) ^ fsw;
    }

    f32x4 acc[5];
#pragma unroll
    for (int nt = 0; nt < 5; ++nt) acc[nt] = (f32x4){0.f, 0.f, 0.f, 0.f};

    float4 ac[4], aw[4];   // held A loads (chunk ch+2)
    bf16x8 wreg0, wreg1;

    // ---- prologue: stage chunk 0 into buf 0; prefetch chunk 1 into regs ----
    {
        float4 c0[4], w0[4];
        if (val) {
#pragma unroll
            for (int i = 0; i < 4; ++i) {
                c0[i] = *(const float4*)(cptr + i * 4);
                w0[i] = *(const float4*)(wptr + i * 4);
            }
        }
        bf16x8 wr0 = *(const bf16x8*)(wgp0);
        bf16x8 wr1 = w2 ? *(const bf16x8*)(wgp1) : (bf16x8)0;
        bf16x8 f0, f1;
        if (val) {
#pragma unroll
            for (int i = 0; i < 2; ++i) {
                f0[i * 4 + 0] = (__bf16)(w0[i].x * rate + c0[i].x * crate);
                f0[i * 4 + 1] = (__bf16)(w0[i].y * rate + c0[i].y * crate);
                f0[i * 4 + 2] = (__bf16)(w0[i].z * rate + c0[i].z * crate);
                f0[i * 4 + 3] = (__bf16)(w0[i].w * rate + c0[i].w * crate);
                f1[i * 4 + 0] = (__bf16)(w0[i + 2].x * rate + c0[i + 2].x * crate);
                f1[i * 4 + 1] = (__bf16)(w0[i + 2].y * rate + c0[i + 2].y * crate);
                f1[i * 4 + 2] = (__bf16)(w0[i + 2].z * rate + c0[i + 2].z * crate);
                f1[i * 4 + 3] = (__bf16)(w0[i + 2].w * rate + c0[i + 2].w * crate);
            }
        } else {
            f0 = (bf16x8)0; f1 = (bf16x8)0;
        }
        *(bf16x8*)(smem + awr0) = f0;
        *(bf16x8*)(smem + awr1) = f1;
        *(bf16x8*)(smem + 32768 + wwr0) = wr0;
        if (w2) *(bf16x8*)(smem + 32768 + wwr1) = wr1;
        // prefetch chunk 1 into regs
        if (val) {
#pragma unroll
            for (int i = 0; i < 4; ++i) {
                ac[i] = *(const float4*)(cptr + CHK + i * 4);
                aw[i] = *(const float4*)(wptr + CHK + i * 4);
            }
        }
        wreg0 = *(const bf16x8*)(wgp0 + CHK);
        wreg1 = w2 ? *(const bf16x8*)(wgp1 + CHK) : (bf16x8)0;
    }
    __syncthreads();

    // ---- main loop ----
    for (int ch = 0; ch < NCH; ++ch) {
        // 1) commit prefetched chunk ch+1 to the other buffer
        if (ch + 1 < NCH) {
            char* An = smem + ((ch + 1) & 1) * 16384;
            char* Wn = smem + 32768 + ((ch + 1) & 1) * 10240;
            bf16x8 f0, f1;
            if (val) {
#pragma unroll
                for (int i = 0; i < 2; ++i) {
                    f0[i * 4 + 0] = (__bf16)(aw[i].x * rate + ac[i].x * crate);
                    f0[i * 4 + 1] = (__bf16)(aw[i].y * rate + ac[i].y * crate);
                    f0[i * 4 + 2] = (__bf16)(aw[i].z * rate + ac[i].z * crate);
                    f0[i * 4 + 3] = (__bf16)(aw[i].w * rate + ac[i].w * crate);
                    f1[i * 4 + 0] = (__bf16)(aw[i + 2].x * rate + ac[i + 2].x * crate);
                    f1[i * 4 + 1] = (__bf16)(aw[i + 2].y * rate + ac[i + 2].y * crate);
                    f1[i * 4 + 2] = (__bf16)(aw[i + 2].z * rate + ac[i + 2].z * crate);
                    f1[i * 4 + 3] = (__bf16)(aw[i + 2].w * rate + ac[i + 2].w * crate);
                }
            } else {
                f0 = (bf16x8)0; f1 = (bf16x8)0;
            }
            *(bf16x8*)(An + awr0) = f0;
            *(bf16x8*)(An + awr1) = f1;
            *(bf16x8*)(Wn + wwr0) = wreg0;
            if (w2) *(bf16x8*)(Wn + wwr1) = wreg1;
        }
        // 2) issue global loads for chunk ch+2 (held in regs across compute)
        if (ch + 2 < NCH) {
            const int ko = (ch + 2) * CHK;
            if (val) {
#pragma unroll
                for (int i = 0; i < 4; ++i) {
                    ac[i] = *(const float4*)(cptr + ko + i * 4);
                    aw[i] = *(const float4*)(wptr + ko + i * 4);
                }
            }
            wreg0 = *(const bf16x8*)(wgp0 + ko);
            wreg1 = w2 ? *(const bf16x8*)(wgp1 + ko) : (bf16x8)0;
        }
        // 3) compute chunk ch
        const char* Ab = smem + (ch & 1) * 16384;
        const char* Wb = smem + 32768 + (ch & 1) * 10240;
#pragma unroll
        for (int s = 0; s < 2; ++s) {
            bf16x8 a = *(const bf16x8*)(Ab + aoff[s]);
#pragma unroll
            for (int nt = 0; nt < 5; ++nt) {
                bf16x8 bw = *(const bf16x8*)(Wb + woff[s][nt]);
                acc[nt] = __builtin_amdgcn_mfma_f32_16x16x32_bf16(a, bw, acc[nt], 0, 0, 0);
            }
        }
        __syncthreads();
    }

    // ---- epilogue: C/D col = lane&15, row = (lane>>4)*4 + reg  [verified R2-R5] ----
    const int obase = (wv < 4) ? (fb + wv * 16) : (bb + (wv - 4) * 16);
    const int orow = obase + kgrp * 4;
#pragma unroll
    for (int nt = 0; nt < 5; ++nt) {
        const int col = nt * 16 + l15;
        if (col < NTAGS) {
            const float bias = b_out[col];
#pragma unroll
            for (int i = 0; i < 4; ++i) {
                out[(size_t)(orow + i) * NTAGS + col] = acc[nt][i] + bias;
            }
        }
    }
}

extern "C" void kernel_launch(void* const* d_in, const int* in_sizes, int n_in,
                              void* d_out, int out_size, void* d_ws, size_t ws_size,
                              hipStream_t stream) {
    const float* out_char = (const float*)d_in[0];
    const float* out_word = (const float*)d_in[1];
    const int* word_idx = (const int*)d_in[2];
    const int* is_head = (const int*)d_in[3];
    const int* valid_mask = (const int*)d_in[4];
    const float* W_out = (const float*)d_in[5];
    const float* b_out = (const float*)d_in[6];
    float* out = (float*)d_out;
    __bf16* Wt = (__bf16*)d_ws;  // 80*1024*2 = 160 KB

    prep_w_kernel<<<HH / 64, 256, 0, stream>>>(W_out, Wt);

    const int rows = 16 * TT;  // B*T = 32768
    slu_main<<<rows / MROWS, THREADS, 0, stream>>>(out_char, out_word, word_idx, is_head,
                                                   valid_mask, Wt, b_out, out);
}